// Round 6
// baseline (296.270 us; speedup 1.0000x reference)
//
#include <hip/hip_runtime.h>
#include <math.h>

// src [B=16,S=4096,DM=768] fp32, mask [B,S] bool, query [H=8,D=96] fp32,
// out [B,768] fp32.
//   w_s = exp(q.k_s)   (scores ~ N(0,1): no max-subtraction needed in fp32)
//   out[b,h,:] = sum_s w_s (k_s + pe_s) / sum_s w_s
// One block per (b, s-chunk of 64 rows); all 8 heads together (lane owns 12
// channels, head = lane>>3, score reduce = 3 shfl_xor width 8). PE inline via
// sin/cos rotation recurrence. R6 delta vs R5: 2-deep software pipeline
// (6 dwordx4 in flight per wave) + full unroll + nontemporal src loads.
namespace {
constexpr int kB = 16;
constexpr int kS = 4096;
constexpr int kH = 8;
constexpr int kD = 96;
constexpr int kDM = 768;
constexpr int kNC = 64;                 // s-chunks per batch -> 1024 blocks
constexpr int kCS = kS / kNC;           // 64 rows per chunk
constexpr int kRW = kCS / 4;            // 16 rows per wave (4 waves/block)
constexpr float kPeScale = 0.03608439182435161f;        // 768^-0.5
constexpr float kNegLog = -9.210340371976184f / 768.0f; // -ln(1e4)/768
}

typedef float v4f __attribute__((ext_vector_type(4)));

__device__ __forceinline__ v4f ldnt4(const float* p) {
    return __builtin_nontemporal_load((const v4f*)p);
}

__global__ __launch_bounds__(256)
void attn_pass1(const float* __restrict__ src,
                const unsigned char* __restrict__ mask,
                const float* __restrict__ query,
                float* __restrict__ wsO,
                float* __restrict__ wsL)
{
    const int blk = (int)blockIdx.x;
    const int b = blk >> 6;             // / kNC
    const int chunk = blk & (kNC - 1);
    const int t = (int)threadIdx.x;
    const int wave = t >> 6;
    const int lane = t & 63;
    const int h = lane >> 3;            // head owning this lane's channels

    // query flat [768]: channel c = h*96+d — same indexing as a src row.
    const float* qf = query + 12 * lane;
    const v4f q0 = *(const v4f*)(qf);
    const v4f q1 = *(const v4f*)(qf + 4);
    const v4f q2 = *(const v4f*)(qf + 8);

    // 6 (sin,cos) channel pairs for this lane: even channels cb+0,2,..,10.
    const int cb = 12 * lane;
    float f[6], sn[6], cs[6], dsn[6], dcs[6];
#pragma unroll
    for (int p = 0; p < 6; ++p)
        f[p] = __expf(kNegLog * (float)(cb + 2 * p));

    // wave handles rows s = chunk*64 + wave + 4*it
    const int s0 = chunk * kCS + wave;
#pragma unroll
    for (int p = 0; p < 6; ++p) {
        __sincosf((float)s0 * f[p], &sn[p], &cs[p]);
        __sincosf(4.0f * f[p], &dsn[p], &dcs[p]);
    }

    float l = 0.0f;
    float o[12];
#pragma unroll
    for (int k = 0; k < 12; ++k) o[k] = 0.0f;

    const float* base = src + ((size_t)b * kS + s0) * kDM + 12 * lane;
    const unsigned char* mb = mask + (size_t)b * kS + s0;

    // ---- 2-deep software pipeline ----
    v4f x0[2], x1[2], x2[2];
    unsigned char mk[2];
    x0[0] = ldnt4(base);
    x1[0] = ldnt4(base + 4);
    x2[0] = ldnt4(base + 8);
    mk[0] = mb[0];
    x0[1] = ldnt4(base + 4 * kDM);
    x1[1] = ldnt4(base + 4 * kDM + 4);
    x2[1] = ldnt4(base + 4 * kDM + 8);
    mk[1] = mb[4];

#pragma unroll
    for (int it = 0; it < kRW; ++it) {
        const int sl = it & 1;
        const v4f a0 = x0[sl];
        const v4f a1 = x1[sl];
        const v4f a2 = x2[sl];
        const unsigned char m = mk[sl];

        if (it + 2 < kRW) {
            const float* np = base + (size_t)((it + 2) * 4) * kDM;
            x0[sl] = ldnt4(np);
            x1[sl] = ldnt4(np + 4);
            x2[sl] = ldnt4(np + 8);
            mk[sl] = mb[(it + 2) * 4];
        }

        float pd = a0[0] * q0[0] + a0[1] * q0[1] + a0[2] * q0[2] + a0[3] * q0[3]
                 + a1[0] * q1[0] + a1[1] * q1[1] + a1[2] * q1[2] + a1[3] * q1[3]
                 + a2[0] * q2[0] + a2[1] * q2[1] + a2[2] * q2[2] + a2[3] * q2[3];
        pd += __shfl_xor(pd, 1, 8);
        pd += __shfl_xor(pd, 2, 8);
        pd += __shfl_xor(pd, 4, 8);     // 8 lanes of the head group share pd

        const float w = m ? 0.0f : __expf(pd);
        l += w;

        // o[c] += w * (x[c] + pe[c]);  even c -> sin, odd c -> cos
        o[0]  = fmaf(w, fmaf(sn[0], kPeScale, a0[0]), o[0]);
        o[1]  = fmaf(w, fmaf(cs[0], kPeScale, a0[1]), o[1]);
        o[2]  = fmaf(w, fmaf(sn[1], kPeScale, a0[2]), o[2]);
        o[3]  = fmaf(w, fmaf(cs[1], kPeScale, a0[3]), o[3]);
        o[4]  = fmaf(w, fmaf(sn[2], kPeScale, a1[0]), o[4]);
        o[5]  = fmaf(w, fmaf(cs[2], kPeScale, a1[1]), o[5]);
        o[6]  = fmaf(w, fmaf(sn[3], kPeScale, a1[2]), o[6]);
        o[7]  = fmaf(w, fmaf(cs[3], kPeScale, a1[3]), o[7]);
        o[8]  = fmaf(w, fmaf(sn[4], kPeScale, a2[0]), o[8]);
        o[9]  = fmaf(w, fmaf(cs[4], kPeScale, a2[1]), o[9]);
        o[10] = fmaf(w, fmaf(sn[5], kPeScale, a2[2]), o[10]);
        o[11] = fmaf(w, fmaf(cs[5], kPeScale, a2[3]), o[11]);

        // rotate phases forward by 4 rows
#pragma unroll
        for (int p = 0; p < 6; ++p) {
            const float ns = fmaf(sn[p], dcs[p], cs[p] * dsn[p]);
            const float nc = fmaf(cs[p], dcs[p], -sn[p] * dsn[p]);
            sn[p] = ns; cs[p] = nc;
        }
    }

    // ---- block reduction across the 4 waves ----
    __shared__ float osum[4][kDM];      // 12 KB
    __shared__ float lsum[4][kH];

    float* op = &osum[wave][12 * lane];
    op[0] = o[0];  op[1] = o[1];  op[2] = o[2];  op[3] = o[3];
    op[4] = o[4];  op[5] = o[5];  op[6] = o[6];  op[7] = o[7];
    op[8] = o[8];  op[9] = o[9];  op[10] = o[10]; op[11] = o[11];
    if ((lane & 7) == 0) lsum[wave][h] = l;
    __syncthreads();

    if (t < kDM / 4) {
        const float4 a0 = ((const float4*)&osum[0][0])[t];
        const float4 a1 = ((const float4*)&osum[1][0])[t];
        const float4 a2 = ((const float4*)&osum[2][0])[t];
        const float4 a3 = ((const float4*)&osum[3][0])[t];
        float4 r;
        r.x = a0.x + a1.x + a2.x + a3.x;
        r.y = a0.y + a1.y + a2.y + a3.y;
        r.z = a0.z + a1.z + a2.z + a3.z;
        r.w = a0.w + a1.w + a2.w + a3.w;
        ((float4*)(wsO + (size_t)blk * kDM))[t] = r;
    }
    if (t < kH) {
        wsL[blk * kH + t] = lsum[0][t] + lsum[1][t] + lsum[2][t] + lsum[3][t];
    }
}

// Combine: one block per batch, 768 threads. Thread d sums the 64 chunk
// partials (coalesced) and divides by its head's weight sum.
__global__ __launch_bounds__(768)
void attn_combine(const float* __restrict__ wsO,
                  const float* __restrict__ wsL,
                  float* __restrict__ out)
{
    const int b = (int)blockIdx.x;
    const int d = (int)threadIdx.x;

    __shared__ float Ls[kH];
    if (d < kH) {
        float L = 0.0f;
#pragma unroll
        for (int cc = 0; cc < kNC; ++cc) L += wsL[(b * kNC + cc) * kH + d];
        Ls[d] = L;
    }
    __syncthreads();

    float acc = 0.0f;
#pragma unroll 8
    for (int cc = 0; cc < kNC; ++cc)
        acc += wsO[(size_t)(b * kNC + cc) * kDM + d];
    out[(size_t)b * kDM + d] = acc / Ls[d / kD];
}

extern "C" void kernel_launch(void* const* d_in, const int* in_sizes, int n_in,
                              void* d_out, int out_size, void* d_ws, size_t ws_size,
                              hipStream_t stream)
{
    const float* src = (const float*)d_in[0];
    const unsigned char* mask = (const unsigned char*)d_in[1];
    const float* query = (const float*)d_in[2];
    float* out = (float*)d_out;

    float* wsO = (float*)d_ws;                              // [1024, 768]
    float* wsL = wsO + (size_t)kB * kNC * kDM;              // [1024, 8]

    hipLaunchKernelGGL(attn_pass1,
                       dim3(kB * kNC), dim3(256), 0, stream,
                       src, mask, query, wsO, wsL);
    hipLaunchKernelGGL(attn_combine,
                       dim3(kB), dim3(kDM), 0, stream,
                       wsO, wsL, out);
}

// Round 7
// 277.163 us; speedup vs baseline: 1.0689x; 1.0689x over previous
//
#include <hip/hip_runtime.h>
#include <math.h>

// src [B=16,S=4096,DM=768] fp32, mask [B,S] bool, query [H=8,D=96] fp32,
// out [B,768] fp32. Single-pass weighted pooling:
//   w_s = exp(q.k_s)  (no max-subtraction: scores ~ N(0,1), fp32-safe)
//   out = sum_s w_s * (k_s + pe_s) / sum_s w_s
// PE computed via sin/cos rotation recurrence (no per-row transcendentals).
// R7 = exact revert to the best-measured variant (R2, 275 us).
namespace {
constexpr int kB = 16;
constexpr int kS = 4096;
constexpr int kH = 8;
constexpr int kD = 96;
constexpr int kDM = 768;
constexpr int kNChunk = 16;            // 16*8*16 = 2048 blocks
constexpr int kCS = kS / kNChunk;      // 256 rows per chunk
constexpr int kRPI = 32;               // 32 row slots in flight (r = t>>3)
constexpr int kIters = kCS / kRPI;     // 8
constexpr float kPeScale = 0.03608439182435161f;        // 768^-0.5
constexpr float kNegLog = -9.210340371976184f / 768.0f; // -ln(1e4)/768
}

// One block per (b,h,chunk). 256 threads: j = t&7 -> 3 float4 of the 96-dim
// row; r = t>>3 -> row slot. Each thread accumulates sum_w and sum_w*(x+pe)
// over its 8 rows; block-level tree merge at the end.
__global__ __launch_bounds__(256)
void attn_partial_kernel(const float* __restrict__ src,
                         const unsigned char* __restrict__ mask,
                         const float* __restrict__ query,
                         float* __restrict__ wsO,
                         float* __restrict__ wsL)
{
    const int blk = blockIdx.x;
    const int chunk = blk % kNChunk;
    const int bh = blk / kNChunk;
    const int b = bh / kH;
    const int h = bh % kH;
    const int t = (int)threadIdx.x;
    const int j = t & 7;
    const int r = t >> 3;
    const int lane = t & 63;
    const int wave = t >> 6;

    const float* qh = query + h * kD + 4 * j;
    const float4 q0 = *(const float4*)(qh);
    const float4 q1 = *(const float4*)(qh + 32);
    const float4 q2 = *(const float4*)(qh + 64);

    // Frequencies for this thread's 6 (sin,cos) channel pairs.
    const int cbase = h * kD + 4 * j;
    const float f0 = __expf(kNegLog * (float)(cbase));
    const float f1 = __expf(kNegLog * (float)(cbase + 2));
    const float f2 = __expf(kNegLog * (float)(cbase + 32));
    const float f3 = __expf(kNegLog * (float)(cbase + 34));
    const float f4 = __expf(kNegLog * (float)(cbase + 64));
    const float f5 = __expf(kNegLog * (float)(cbase + 66));

    // Initial phase at s0 = chunk*kCS + r; rotation step for ds = kRPI rows.
    const float s0f = (float)(chunk * kCS + r);
    float sn0, cs0, sn1, cs1, sn2, cs2, sn3, cs3, sn4, cs4, sn5, cs5;
    __sincosf(s0f * f0, &sn0, &cs0);
    __sincosf(s0f * f1, &sn1, &cs1);
    __sincosf(s0f * f2, &sn2, &cs2);
    __sincosf(s0f * f3, &sn3, &cs3);
    __sincosf(s0f * f4, &sn4, &cs4);
    __sincosf(s0f * f5, &sn5, &cs5);
    float dsn0, dcs0, dsn1, dcs1, dsn2, dcs2, dsn3, dcs3, dsn4, dcs4, dsn5, dcs5;
    __sincosf((float)kRPI * f0, &dsn0, &dcs0);
    __sincosf((float)kRPI * f1, &dsn1, &dcs1);
    __sincosf((float)kRPI * f2, &dsn2, &dcs2);
    __sincosf((float)kRPI * f3, &dsn3, &dcs3);
    __sincosf((float)kRPI * f4, &dsn4, &dcs4);
    __sincosf((float)kRPI * f5, &dsn5, &dcs5);

    float l = 0.0f;
    float o[12];
#pragma unroll
    for (int k = 0; k < 12; ++k) o[k] = 0.0f;

    const float* baseT = src + ((size_t)b * kS + (size_t)(chunk * kCS + r)) * kDM
                       + h * kD + 4 * j;
    const unsigned char* mbase = mask + (size_t)b * kS + chunk * kCS + r;

    // software pipeline: loads for iteration it+1 issued before compute of it
    float4 x0 = *(const float4*)(baseT);
    float4 x1 = *(const float4*)(baseT + 32);
    float4 x2 = *(const float4*)(baseT + 64);
    unsigned char mk = mbase[0];

#pragma unroll
    for (int it = 0; it < kIters; ++it) {
        float4 nx0 = {}, nx1 = {}, nx2 = {};
        unsigned char nmk = 0;
        if (it + 1 < kIters) {
            const float* np = baseT + (size_t)(it + 1) * kRPI * kDM;
            nx0 = *(const float4*)(np);
            nx1 = *(const float4*)(np + 32);
            nx2 = *(const float4*)(np + 64);
            nmk = mbase[(it + 1) * kRPI];
        }

        // score = q . key (partial dot, reduce across the 8 lanes of the row)
        float pd = x0.x * q0.x + x0.y * q0.y + x0.z * q0.z + x0.w * q0.w
                 + x1.x * q1.x + x1.y * q1.y + x1.z * q1.z + x1.w * q1.w
                 + x2.x * q2.x + x2.y * q2.y + x2.z * q2.z + x2.w * q2.w;
        pd += __shfl_xor(pd, 1, 8);
        pd += __shfl_xor(pd, 2, 8);
        pd += __shfl_xor(pd, 4, 8);

        const float w = mk ? 0.0f : __expf(pd);
        l += w;

        o[0]  = fmaf(w, fmaf(sn0, kPeScale, x0.x), o[0]);
        o[1]  = fmaf(w, fmaf(cs0, kPeScale, x0.y), o[1]);
        o[2]  = fmaf(w, fmaf(sn1, kPeScale, x0.z), o[2]);
        o[3]  = fmaf(w, fmaf(cs1, kPeScale, x0.w), o[3]);
        o[4]  = fmaf(w, fmaf(sn2, kPeScale, x1.x), o[4]);
        o[5]  = fmaf(w, fmaf(cs2, kPeScale, x1.y), o[5]);
        o[6]  = fmaf(w, fmaf(sn3, kPeScale, x1.z), o[6]);
        o[7]  = fmaf(w, fmaf(cs3, kPeScale, x1.w), o[7]);
        o[8]  = fmaf(w, fmaf(sn4, kPeScale, x2.x), o[8]);
        o[9]  = fmaf(w, fmaf(cs4, kPeScale, x2.y), o[9]);
        o[10] = fmaf(w, fmaf(sn5, kPeScale, x2.z), o[10]);
        o[11] = fmaf(w, fmaf(cs5, kPeScale, x2.w), o[11]);

        // rotate phases forward by kRPI rows (4 FMA-class ops per pair)
        float tns, tnc;
        tns = fmaf(sn0, dcs0, cs0 * dsn0); tnc = fmaf(cs0, dcs0, -sn0 * dsn0); sn0 = tns; cs0 = tnc;
        tns = fmaf(sn1, dcs1, cs1 * dsn1); tnc = fmaf(cs1, dcs1, -sn1 * dsn1); sn1 = tns; cs1 = tnc;
        tns = fmaf(sn2, dcs2, cs2 * dsn2); tnc = fmaf(cs2, dcs2, -sn2 * dsn2); sn2 = tns; cs2 = tnc;
        tns = fmaf(sn3, dcs3, cs3 * dsn3); tnc = fmaf(cs3, dcs3, -sn3 * dsn3); sn3 = tns; cs3 = tnc;
        tns = fmaf(sn4, dcs4, cs4 * dsn4); tnc = fmaf(cs4, dcs4, -sn4 * dsn4); sn4 = tns; cs4 = tnc;
        tns = fmaf(sn5, dcs5, cs5 * dsn5); tnc = fmaf(cs5, dcs5, -sn5 * dsn5); sn5 = tns; cs5 = tnc;

        x0 = nx0; x1 = nx1; x2 = nx2; mk = nmk;
    }

    // ---- block-level merge (plain sums, no max bookkeeping) ----
    __shared__ float ssum[4];
    __shared__ float osh[4][8][12];

    // L: one representative lane (j==0) per row group
    float lv = (j == 0) ? l : 0.0f;
#pragma unroll
    for (int msk = 32; msk >= 1; msk >>= 1) lv += __shfl_xor(lv, msk, 64);
    if (lane == 0) ssum[wave] = lv;

    // O: sum across the 8 row groups within the wave (keeps j fixed)
#pragma unroll
    for (int k = 0; k < 12; ++k) {
        float v = o[k];
        v += __shfl_xor(v, 8, 64);
        v += __shfl_xor(v, 16, 64);
        v += __shfl_xor(v, 32, 64);
        o[k] = v;
    }
    if (lane < 8) {
#pragma unroll
        for (int k = 0; k < 12; ++k) osh[wave][lane][k] = o[k];
    }
    __syncthreads();

    const int pidx = bh * kNChunk + chunk;
    if (t < kD) {
        const int kk = t >> 5;
        const int jj = (t & 31) >> 2;
        const int qq = t & 3;
        const int idx = kk * 4 + qq;
        wsO[(size_t)pidx * kD + t] = osh[0][jj][idx] + osh[1][jj][idx]
                                   + osh[2][jj][idx] + osh[3][jj][idx];
    }
    if (t == 0) {
        wsL[pidx] = ssum[0] + ssum[1] + ssum[2] + ssum[3];
    }
}

// Merge kNChunk partials per (b,h): out = sum_c O_c / sum_c L_c.
__global__ __launch_bounds__(128)
void attn_combine_kernel(const float* __restrict__ wsO,
                         const float* __restrict__ wsL,
                         float* __restrict__ out)
{
    const int bh = (int)blockIdx.x;
    const int t = (int)threadIdx.x;

    float L = 0.0f;
#pragma unroll
    for (int c = 0; c < kNChunk; ++c) L += wsL[bh * kNChunk + c];

    if (t < kD) {
        float Od = 0.0f;
#pragma unroll
        for (int c = 0; c < kNChunk; ++c)
            Od += wsO[(size_t)(bh * kNChunk + c) * kD + t];
        out[(size_t)bh * kD + t] = Od / L;
    }
}

extern "C" void kernel_launch(void* const* d_in, const int* in_sizes, int n_in,
                              void* d_out, int out_size, void* d_ws, size_t ws_size,
                              hipStream_t stream)
{
    const float* src = (const float*)d_in[0];
    const unsigned char* mask = (const unsigned char*)d_in[1];
    const float* query = (const float*)d_in[2];
    float* out = (float*)d_out;

    float* wsO = (float*)d_ws;                              // [2048, 96]
    float* wsL = wsO + (size_t)kB * kH * kNChunk * kD;      // [2048]

    hipLaunchKernelGGL(attn_partial_kernel,
                       dim3(kB * kH * kNChunk), dim3(256), 0, stream,
                       src, mask, query, wsO, wsL);
    hipLaunchKernelGGL(attn_combine_kernel,
                       dim3(kB * kH), dim3(128), 0, stream,
                       wsO, wsL, out);
}